// Round 1
// baseline (1519.417 us; speedup 1.0000x reference)
//
#include <hip/hip_runtime.h>

#define NN 50000
#define NE 800000
#define CIN 128
#define CH 128
#define COUT 64
#define NG 256

// ---------------------------------------------------------------------------
// 1) degree of dst (self-loop added as +1 later)
__global__ __launch_bounds__(256) void k_deg(const int* __restrict__ dst,
                                             int* __restrict__ deg) {
    int t = blockIdx.x * 256 + threadIdx.x;
    if (t < NE) atomicAdd(&deg[dst[t]], 1);
}

// 2) dinv = rsqrt(deg + 1)
__global__ __launch_bounds__(256) void k_dinv(const int* __restrict__ deg,
                                              float* __restrict__ dinv) {
    int t = blockIdx.x * 256 + threadIdx.x;
    if (t < NN) dinv[t] = rsqrtf((float)(deg[t] + 1));
}

// 3) h = x @ W1  (M=50000, K=128, N=128) fp32
//    block: 256 thr, tile 32 rows x 128 cols; thread -> 16 rows x 1 col.
//    xs in LDS (broadcast reads across the 64 cols of a wave), W via L1/L2.
__global__ __launch_bounds__(256) void k_gemm1(const float* __restrict__ x,
                                               const float* __restrict__ W,
                                               float* __restrict__ h) {
    __shared__ float xs[32 * 128];
    const int tid = threadIdx.x;
    const int r0 = blockIdx.x * 32;
    for (int i = tid * 4; i < 32 * 128; i += 256 * 4) {
        int r = i >> 7, c = i & 127;
        int gr = r0 + r;
        float4 v = make_float4(0.f, 0.f, 0.f, 0.f);
        if (gr < NN) v = *(const float4*)(x + (size_t)gr * 128 + c);
        *(float4*)(xs + i) = v;
    }
    __syncthreads();
    const int col = tid & 127;
    const int rbase = (tid >> 7) * 16;
    float acc[16];
#pragma unroll
    for (int r = 0; r < 16; ++r) acc[r] = 0.f;
    for (int k = 0; k < 128; k += 4) {
        float w0 = W[(k + 0) * 128 + col];
        float w1 = W[(k + 1) * 128 + col];
        float w2 = W[(k + 2) * 128 + col];
        float w3 = W[(k + 3) * 128 + col];
#pragma unroll
        for (int r = 0; r < 16; ++r) {
            float4 xv = *(const float4*)(xs + (rbase + r) * 128 + k);
            acc[r] += xv.x * w0 + xv.y * w1 + xv.z * w2 + xv.w * w3;
        }
    }
#pragma unroll
    for (int r = 0; r < 16; ++r) {
        int gr = r0 + rbase + r;
        if (gr < NN) h[(size_t)gr * 128 + col] = acc[r];
    }
}

// 4) edge scatter: agg[dst] += h[src] * dinv[src]*dinv[dst]
//    32 lanes per edge, float4 per lane.
__global__ __launch_bounds__(256) void k_scatter(const float* __restrict__ h,
                                                 const int* __restrict__ src,
                                                 const int* __restrict__ dst,
                                                 const float* __restrict__ dinv,
                                                 float* __restrict__ agg) {
    int t = blockIdx.x * 256 + threadIdx.x;
    int e = t >> 5;
    if (e >= NE) return;
    int c = (t & 31) * 4;
    int s = src[e], d = dst[e];
    float nrm = dinv[s] * dinv[d];
    float4 v = *(const float4*)(h + (size_t)s * 128 + c);
    float* a = agg + (size_t)d * 128 + c;
    atomicAdd(a + 0, v.x * nrm);
    atomicAdd(a + 1, v.y * nrm);
    atomicAdd(a + 2, v.z * nrm);
    atomicAdd(a + 3, v.w * nrm);
}

// 5) self-loop + bias + relu + segment-max pool (batch is sorted!)
//    block: 128 thr (one per channel), 32 consecutive nodes; running max,
//    flush atomicMax on batch-id change. Non-negative floats: int compare ok.
__global__ __launch_bounds__(128) void k_pool(const float* __restrict__ agg,
                                              const float* __restrict__ h,
                                              const float* __restrict__ dinv,
                                              const float* __restrict__ b1,
                                              const int* __restrict__ batch,
                                              int* __restrict__ pooled) {
    const int c = threadIdx.x;            // 0..127
    const int n0 = blockIdx.x * 32;
    const int n1 = (n0 + 32 < NN) ? n0 + 32 : NN;
    const float bc = b1[c];
    float m = 0.f;
    int cur = -1;
    for (int n = n0; n < n1; ++n) {
        int b = batch[n];
        float di = dinv[n];
        float v = agg[(size_t)n * 128 + c] + h[(size_t)n * 128 + c] * (di * di) + bc;
        v = fmaxf(v, 0.f);
        if (b != cur) {
            if (cur >= 0) atomicMax(&pooled[cur * 128 + c], __float_as_int(m));
            cur = b;
            m = v;
        } else {
            m = fmaxf(m, v);
        }
    }
    if (cur >= 0) atomicMax(&pooled[cur * 128 + c], __float_as_int(m));
}

// 6) out = relu(pooled @ W2 + b2)   (256x128 @ 128x64)
__global__ __launch_bounds__(256) void k_gemm2(const float* __restrict__ pooled,
                                               const float* __restrict__ W2,
                                               const float* __restrict__ b2,
                                               float* __restrict__ out) {
    const int tid = threadIdx.x;
    const int row = blockIdx.x * 4 + (tid >> 6);
    const int col = tid & 63;
    const float* p = pooled + row * 128;
    float acc = b2[col];
    for (int k = 0; k < 128; ++k) acc += p[k] * W2[k * 64 + col];
    out[row * 64 + col] = fmaxf(acc, 0.f);
}

extern "C" void kernel_launch(void* const* d_in, const int* in_sizes, int n_in,
                              void* d_out, int out_size, void* d_ws, size_t ws_size,
                              hipStream_t stream) {
    const float* x     = (const float*)d_in[0];
    const int*   ei    = (const int*)d_in[1];   // [2, NE]: src row then dst row
    const int*   batch = (const int*)d_in[2];
    const float* W1    = (const float*)d_in[3];
    const float* b1    = (const float*)d_in[4];
    const float* W2    = (const float*)d_in[5];
    const float* b2    = (const float*)d_in[6];
    float* out = (float*)d_out;

    // workspace layout (floats): agg | pooled | deg | dinv | h
    float* agg    = (float*)d_ws;                       // NN*128
    float* pooled = agg + (size_t)NN * 128;             // NG*128
    int*   deg    = (int*)(pooled + (size_t)NG * 128);  // NN
    float* dinv   = (float*)(deg + NN);                 // NN
    float* h      = dinv + NN;                          // NN*128

    // zero agg + pooled + deg in one memset (capture-safe)
    size_t zbytes = ((size_t)NN * 128 + (size_t)NG * 128 + (size_t)NN) * sizeof(float);
    hipMemsetAsync(d_ws, 0, zbytes, stream);

    const int* srcv = ei;
    const int* dstv = ei + NE;

    k_deg<<<(NE + 255) / 256, 256, 0, stream>>>(dstv, deg);
    k_dinv<<<(NN + 255) / 256, 256, 0, stream>>>(deg, dinv);
    k_gemm1<<<(NN + 31) / 32, 256, 0, stream>>>(x, W1, h);
    {
        long long threads = (long long)NE * 32;
        int blocks = (int)((threads + 255) / 256);
        k_scatter<<<blocks, 256, 0, stream>>>(h, srcv, dstv, dinv, agg);
    }
    k_pool<<<(NN + 31) / 32, 128, 0, stream>>>(agg, h, dinv, b1, batch, (int*)pooled);
    k_gemm2<<<NG / 4, 256, 0, stream>>>(pooled, W2, b2, out);
}

// Round 2
// 364.225 us; speedup vs baseline: 4.1716x; 4.1716x over previous
//
#include <hip/hip_runtime.h>

#define NN 50000
#define NE 800000
#define CIN 128
#define CH 128
#define COUT 64
#define NG 256

// ---------------------------------------------------------------------------
// 1) degree of dst (self-loop handled separately as +1)
__global__ __launch_bounds__(256) void k_deg(const int* __restrict__ dst,
                                             int* __restrict__ deg) {
    int t = blockIdx.x * 256 + threadIdx.x;
    if (t < NE) atomicAdd(&deg[dst[t]], 1);
}

// 2) dinv = rsqrt(deg + 1)
__global__ __launch_bounds__(256) void k_dinv(const int* __restrict__ deg,
                                              float* __restrict__ dinv) {
    int t = blockIdx.x * 256 + threadIdx.x;
    if (t < NN) dinv[t] = rsqrtf((float)(deg[t] + 1));
}

// 3) exclusive scan of deg -> rowptr (single block, 1024 threads, 49 elems/thread)
__global__ __launch_bounds__(1024) void k_scan(const int* __restrict__ deg,
                                               int* __restrict__ rowptr) {
    __shared__ int part[1024];
    const int t = threadIdx.x;
    const int CHK = 49;                      // 49*1024 = 50176 >= NN
    int b0 = t * CHK;
    int b1 = b0 + CHK < NN ? b0 + CHK : NN;
    int s = 0;
    for (int i = b0; i < b1; ++i) s += deg[i];
    part[t] = s;
    __syncthreads();
    for (int off = 1; off < 1024; off <<= 1) {   // Hillis-Steele inclusive
        int v = (t >= off) ? part[t - off] : 0;
        __syncthreads();
        part[t] += v;
        __syncthreads();
    }
    int run = part[t] - s;                   // exclusive prefix for this chunk
    for (int i = b0; i < b1; ++i) { rowptr[i] = run; run += deg[i]; }
}

// 4) CSR build with cursor trick: rowptr becomes end-pointer after this pass;
//    segment for node d = [rowptr[d]-deg[d], rowptr[d]).
__global__ __launch_bounds__(256) void k_csr(const int* __restrict__ src,
                                             const int* __restrict__ dst,
                                             int* __restrict__ rowptr,
                                             int* __restrict__ csr_src) {
    int t = blockIdx.x * 256 + threadIdx.x;
    if (t < NE) {
        int d = dst[t];
        int pos = atomicAdd(&rowptr[d], 1);
        csr_src[pos] = src[t];
    }
}

// 5) h = x @ W1  (M=50000, K=128, N=128) fp32
__global__ __launch_bounds__(256) void k_gemm1(const float* __restrict__ x,
                                               const float* __restrict__ W,
                                               float* __restrict__ h) {
    __shared__ float xs[32 * 128];
    const int tid = threadIdx.x;
    const int r0 = blockIdx.x * 32;
    for (int i = tid * 4; i < 32 * 128; i += 256 * 4) {
        int r = i >> 7, c = i & 127;
        int gr = r0 + r;
        float4 v = make_float4(0.f, 0.f, 0.f, 0.f);
        if (gr < NN) v = *(const float4*)(x + (size_t)gr * 128 + c);
        *(float4*)(xs + i) = v;
    }
    __syncthreads();
    const int col = tid & 127;
    const int rbase = (tid >> 7) * 16;
    float acc[16];
#pragma unroll
    for (int r = 0; r < 16; ++r) acc[r] = 0.f;
    for (int k = 0; k < 128; k += 4) {
        float w0 = W[(k + 0) * 128 + col];
        float w1 = W[(k + 1) * 128 + col];
        float w2 = W[(k + 2) * 128 + col];
        float w3 = W[(k + 3) * 128 + col];
#pragma unroll
        for (int r = 0; r < 16; ++r) {
            float4 xv = *(const float4*)(xs + (rbase + r) * 128 + k);
            acc[r] += xv.x * w0 + xv.y * w1 + xv.z * w2 + xv.w * w3;
        }
    }
#pragma unroll
    for (int r = 0; r < 16; ++r) {
        int gr = r0 + rbase + r;
        if (gr < NN) h[(size_t)gr * 128 + col] = acc[r];
    }
}

// 6) aggregation + self-loop + bias + relu + fused max-pool.
//    One wave per dst node (4 nodes / 256-thread block); lane owns 2 channels.
//    Pool flush: batch is sorted, so per block we emit ~1 atomicMax run.
__global__ __launch_bounds__(256) void k_agg(const float* __restrict__ h,
                                             const int* __restrict__ csr_src,
                                             const int* __restrict__ rowptr,
                                             const int* __restrict__ deg,
                                             const float* __restrict__ dinv,
                                             const float* __restrict__ b1,
                                             const int* __restrict__ batch,
                                             int* __restrict__ pooled) {
    const int tid = threadIdx.x;
    const int w = tid >> 6, lane = tid & 63;
    const int n = blockIdx.x * 4 + w;        // NN = 50000 = 12500*4, no tail
    __shared__ float vals[4][128];
    __shared__ int bts[4];
    const float dd = dinv[n];
    const int end = rowptr[n];               // post-csr cursor = orig rowptr[n+1]
    const int beg = end - deg[n];
    const int c = lane * 2;
    float ax = 0.f, ay = 0.f;
    int i = beg;
#pragma unroll 2
    for (; i < end; ++i) {
        int s = csr_src[i];
        float nr = dinv[s] * dd;
        float2 v = *(const float2*)(h + (size_t)s * 128 + c);
        ax += v.x * nr;
        ay += v.y * nr;
    }
    float2 hv = *(const float2*)(h + (size_t)n * 128 + c);
    float sl = dd * dd;
    ax = fmaxf(ax + hv.x * sl + b1[c], 0.f);
    ay = fmaxf(ay + hv.y * sl + b1[c + 1], 0.f);
    vals[w][c] = ax;
    vals[w][c + 1] = ay;
    if (lane == 0) bts[w] = batch[n];
    __syncthreads();
    if (tid < 128) {
        float m = vals[0][tid];
        int cur = bts[0];
#pragma unroll
        for (int ww = 1; ww < 4; ++ww) {
            if (bts[ww] != cur) {
                atomicMax(&pooled[cur * 128 + tid], __float_as_int(m));
                cur = bts[ww];
                m = vals[ww][tid];
            } else {
                m = fmaxf(m, vals[ww][tid]);
            }
        }
        atomicMax(&pooled[cur * 128 + tid], __float_as_int(m));
    }
}

// 7) out = relu(pooled @ W2 + b2)   (256x128 @ 128x64)
__global__ __launch_bounds__(256) void k_gemm2(const float* __restrict__ pooled,
                                               const float* __restrict__ W2,
                                               const float* __restrict__ b2,
                                               float* __restrict__ out) {
    const int tid = threadIdx.x;
    const int row = blockIdx.x * 4 + (tid >> 6);
    const int col = tid & 63;
    const float* p = pooled + row * 128;
    float acc = b2[col];
    for (int k = 0; k < 128; ++k) acc += p[k] * W2[k * 64 + col];
    out[row * 64 + col] = fmaxf(acc, 0.f);
}

extern "C" void kernel_launch(void* const* d_in, const int* in_sizes, int n_in,
                              void* d_out, int out_size, void* d_ws, size_t ws_size,
                              hipStream_t stream) {
    const float* x     = (const float*)d_in[0];
    const int*   ei    = (const int*)d_in[1];   // [2, NE]: src row then dst row
    const int*   batch = (const int*)d_in[2];
    const float* W1    = (const float*)d_in[3];
    const float* b1    = (const float*)d_in[4];
    const float* W2    = (const float*)d_in[5];
    const float* b2    = (const float*)d_in[6];
    float* out = (float*)d_out;

    // ws layout (ints/floats, 4B each):
    // [zeroed: deg (NN) | pooled (NG*128)] rowptr (NN) | dinv (NN) | csr_src (NE) | h (NN*128)
    int*   deg     = (int*)d_ws;
    int*   pooled  = deg + NN;
    int*   rowptr  = pooled + (size_t)NG * 128;
    float* dinv    = (float*)(rowptr + NN);
    int*   csr_src = (int*)(dinv + NN);
    float* h       = (float*)(csr_src + NE);

    size_t zbytes = ((size_t)NN + (size_t)NG * 128) * 4;
    hipMemsetAsync(d_ws, 0, zbytes, stream);

    const int* srcv = ei;
    const int* dstv = ei + NE;

    k_deg<<<(NE + 255) / 256, 256, 0, stream>>>(dstv, deg);
    k_dinv<<<(NN + 255) / 256, 256, 0, stream>>>(deg, dinv);
    k_scan<<<1, 1024, 0, stream>>>(deg, rowptr);
    k_csr<<<(NE + 255) / 256, 256, 0, stream>>>(srcv, dstv, rowptr, csr_src);
    k_gemm1<<<(NN + 31) / 32, 256, 0, stream>>>(x, W1, h);
    k_agg<<<NN / 4, 256, 0, stream>>>(h, csr_src, rowptr, deg, dinv, b1, batch, pooled);
    k_gemm2<<<NG / 4, 256, 0, stream>>>((const float*)pooled, W2, b2, out);
}

// Round 3
// 249.794 us; speedup vs baseline: 6.0827x; 1.4581x over previous
//
#include <hip/hip_runtime.h>

#define NN 50000
#define NE 800000
#define NG 256
#define NBLK 98   // ceil(NN/512)

static __device__ __forceinline__ unsigned short f2b(float f) {
    // round-to-nearest-even fp32 -> bf16 (finite values only)
    unsigned int u = __float_as_uint(f);
    return (unsigned short)((u + 0x7FFFu + ((u >> 16) & 1u)) >> 16);
}
static __device__ __forceinline__ float blo(unsigned int v) {
    return __uint_as_float((v & 0xFFFFu) << 16);
}
static __device__ __forceinline__ float bhi(unsigned int v) {
    return __uint_as_float(v & 0xFFFF0000u);
}

// 1) degree of dst (self-loop handled as +1 later)
__global__ __launch_bounds__(256) void k_deg(const int* __restrict__ dst,
                                             int* __restrict__ deg) {
    int t = blockIdx.x * 256 + threadIdx.x;
    if (t < NE) atomicAdd(&deg[dst[t]], 1);
}

// 2a) per-512-chunk sums
__global__ __launch_bounds__(256) void k_scanA(const int* __restrict__ deg,
                                               int* __restrict__ bsum) {
    __shared__ int r[256];
    int t = threadIdx.x;
    int i0 = blockIdx.x * 512 + t * 2;
    int s = 0;
    if (i0 < NN) s += deg[i0];
    if (i0 + 1 < NN) s += deg[i0 + 1];
    r[t] = s;
    __syncthreads();
    for (int off = 128; off > 0; off >>= 1) {
        if (t < off) r[t] += r[t + off];
        __syncthreads();
    }
    if (t == 0) bsum[blockIdx.x] = r[0];
}

// 2b) exclusive scan of the 98 partials (tiny)
__global__ __launch_bounds__(128) void k_scanB(const int* __restrict__ bsum,
                                               int* __restrict__ boff) {
    __shared__ int ps[128];
    int t = threadIdx.x;
    int v = (t < NBLK) ? bsum[t] : 0;
    ps[t] = v;
    __syncthreads();
    for (int off = 1; off < 128; off <<= 1) {
        int u = (t >= off) ? ps[t - off] : 0;
        __syncthreads();
        ps[t] += u;
        __syncthreads();
    }
    if (t < NBLK) boff[t] = ps[t] - v;
}

// 2c) rowptr = exclusive scan of deg (per block + offset); fused dinv
__global__ __launch_bounds__(256) void k_scanC(const int* __restrict__ deg,
                                               const int* __restrict__ boff,
                                               int* __restrict__ rowptr,
                                               float* __restrict__ dinv) {
    __shared__ int ps[256];
    int t = threadIdx.x;
    int i0 = blockIdx.x * 512 + t * 2;
    int d0 = (i0 < NN) ? deg[i0] : 0;
    int d1 = (i0 + 1 < NN) ? deg[i0 + 1] : 0;
    int p = d0 + d1;
    ps[t] = p;
    __syncthreads();
    for (int off = 1; off < 256; off <<= 1) {
        int u = (t >= off) ? ps[t - off] : 0;
        __syncthreads();
        ps[t] += u;
        __syncthreads();
    }
    int e = boff[blockIdx.x] + ps[t] - p;
    if (i0 < NN)     { rowptr[i0] = e;          dinv[i0] = rsqrtf((float)(d0 + 1)); }
    if (i0 + 1 < NN) { rowptr[i0 + 1] = e + d0; dinv[i0 + 1] = rsqrtf((float)(d1 + 1)); }
}

// 3) CSR build, cursor trick: rowptr[d] becomes segment END after this pass
__global__ __launch_bounds__(256) void k_csr(const int* __restrict__ src,
                                             const int* __restrict__ dst,
                                             int* __restrict__ rowptr,
                                             int* __restrict__ csr_src) {
    int t = blockIdx.x * 256 + threadIdx.x;
    if (t < NE) {
        int d = dst[t];
        int pos = atomicAdd(&rowptr[d], 1);
        csr_src[pos] = src[t];
    }
}

// 4) h(bf16) = x @ W1 (fp32 accumulate). 64x64 tile/block, K-chunks of 64,
//    4x4 outer product per thread; k-major LDS tiles, conflict-free b128 reads.
__global__ __launch_bounds__(256) void k_gemm1(const float* __restrict__ x,
                                               const float* __restrict__ W,
                                               unsigned short* __restrict__ h) {
    __shared__ float As[64][64];   // [kk][row]
    __shared__ float Ws[64][64];   // [kk][col]
    const int tid = threadIdx.x;
    const int mt = blockIdx.x >> 1;
    const int c0 = (blockIdx.x & 1) * 64;
    const int r0 = mt * 64;
    const int ty = tid >> 4, tx = tid & 15;
    float acc[4][4];
#pragma unroll
    for (int i = 0; i < 4; ++i)
#pragma unroll
        for (int j = 0; j < 4; ++j) acc[i][j] = 0.f;

    for (int kc = 0; kc < 128; kc += 64) {
        // stage x-tile transposed: row = tid&63
        {
            int row = tid & 63;
            int gr = r0 + row;
#pragma unroll
            for (int p = 0; p < 4; ++p) {
                int kk = p * 16 + (tid >> 6) * 4;
                float4 v = make_float4(0.f, 0.f, 0.f, 0.f);
                if (gr < NN) v = *(const float4*)(x + (size_t)gr * 128 + kc + kk);
                As[kk + 0][row] = v.x;
                As[kk + 1][row] = v.y;
                As[kk + 2][row] = v.z;
                As[kk + 3][row] = v.w;
            }
        }
        // stage W-tile (already k-major in global)
        {
            int c4 = (tid & 15) * 4;
#pragma unroll
            for (int p = 0; p < 4; ++p) {
                int kk = p * 16 + (tid >> 4);
                float4 v = *(const float4*)(W + (size_t)(kc + kk) * 128 + c0 + c4);
                *(float4*)&Ws[kk][c4] = v;
            }
        }
        __syncthreads();
#pragma unroll 4
        for (int kk = 0; kk < 64; ++kk) {
            float4 a4 = *(const float4*)&As[kk][ty * 4];
            float4 b4 = *(const float4*)&Ws[kk][tx * 4];
            float a[4] = {a4.x, a4.y, a4.z, a4.w};
            float b[4] = {b4.x, b4.y, b4.z, b4.w};
#pragma unroll
            for (int i = 0; i < 4; ++i)
#pragma unroll
                for (int j = 0; j < 4; ++j) acc[i][j] += a[i] * b[j];
        }
        __syncthreads();
    }
#pragma unroll
    for (int i = 0; i < 4; ++i) {
        int gr = r0 + ty * 4 + i;
        if (gr < NN) {
            ushort4 o;
            o.x = f2b(acc[i][0]);
            o.y = f2b(acc[i][1]);
            o.z = f2b(acc[i][2]);
            o.w = f2b(acc[i][3]);
            *(ushort4*)(h + (size_t)gr * 128 + c0 + tx * 4) = o;
        }
    }
}

// 5) aggregation (bf16 gather) + self-loop + bias + relu + fused max-pool
__global__ __launch_bounds__(256) void k_agg(const unsigned short* __restrict__ h,
                                             const int* __restrict__ csr_src,
                                             const int* __restrict__ rowptr,
                                             const int* __restrict__ deg,
                                             const float* __restrict__ dinv,
                                             const float* __restrict__ b1,
                                             const int* __restrict__ batch,
                                             int* __restrict__ pooled) {
    const int tid = threadIdx.x;
    const int w = tid >> 6, lane = tid & 63;
    const int n = blockIdx.x * 4 + w;        // NN = 50000 = 12500*4
    __shared__ float vals[4][128];
    __shared__ int bts[4];
    const float dd = dinv[n];
    const int end = rowptr[n];               // cursor end after k_csr
    const int beg = end - deg[n];
    const int c = lane * 2;
    float ax = 0.f, ay = 0.f;
#pragma unroll 4
    for (int i = beg; i < end; ++i) {
        int s = csr_src[i];
        float nr = dinv[s] * dd;
        unsigned int v = *(const unsigned int*)(h + (size_t)s * 128 + c);
        ax += blo(v) * nr;
        ay += bhi(v) * nr;
    }
    unsigned int v = *(const unsigned int*)(h + (size_t)n * 128 + c);
    float sl = dd * dd;
    ax = fmaxf(ax + blo(v) * sl + b1[c], 0.f);
    ay = fmaxf(ay + bhi(v) * sl + b1[c + 1], 0.f);
    vals[w][c] = ax;
    vals[w][c + 1] = ay;
    if (lane == 0) bts[w] = batch[n];
    __syncthreads();
    if (tid < 128) {
        float m = vals[0][tid];
        int cur = bts[0];
#pragma unroll
        for (int ww = 1; ww < 4; ++ww) {
            if (bts[ww] != cur) {
                atomicMax(&pooled[cur * 128 + tid], __float_as_int(m));
                cur = bts[ww];
                m = vals[ww][tid];
            } else {
                m = fmaxf(m, vals[ww][tid]);
            }
        }
        atomicMax(&pooled[cur * 128 + tid], __float_as_int(m));
    }
}

// 6) out = relu(pooled @ W2 + b2)
__global__ __launch_bounds__(256) void k_gemm2(const float* __restrict__ pooled,
                                               const float* __restrict__ W2,
                                               const float* __restrict__ b2,
                                               float* __restrict__ out) {
    const int tid = threadIdx.x;
    const int row = blockIdx.x * 4 + (tid >> 6);
    const int col = tid & 63;
    const float* p = pooled + row * 128;
    float acc = b2[col];
    for (int k = 0; k < 128; ++k) acc += p[k] * W2[k * 64 + col];
    out[row * 64 + col] = fmaxf(acc, 0.f);
}

extern "C" void kernel_launch(void* const* d_in, const int* in_sizes, int n_in,
                              void* d_out, int out_size, void* d_ws, size_t ws_size,
                              hipStream_t stream) {
    const float* x     = (const float*)d_in[0];
    const int*   ei    = (const int*)d_in[1];   // [2, NE]: src row then dst row
    const int*   batch = (const int*)d_in[2];
    const float* W1    = (const float*)d_in[3];
    const float* b1    = (const float*)d_in[4];
    const float* W2    = (const float*)d_in[5];
    const float* b2    = (const float*)d_in[6];
    float* out = (float*)d_out;

    // ws layout (4B units):
    // [zeroed: deg NN | pooled NG*128] rowptr NN | dinv NN | bsum 128 | boff 128 | csr_src NE | h (bf16, NN*128 ushort)
    int*   deg     = (int*)d_ws;
    int*   pooled  = deg + NN;
    int*   rowptr  = pooled + (size_t)NG * 128;
    float* dinv    = (float*)(rowptr + NN);
    int*   bsum    = (int*)(dinv + NN);
    int*   boff    = bsum + 128;
    int*   csr_src = boff + 128;
    unsigned short* h = (unsigned short*)(csr_src + NE);

    size_t zbytes = ((size_t)NN + (size_t)NG * 128) * 4;
    hipMemsetAsync(d_ws, 0, zbytes, stream);

    const int* srcv = ei;
    const int* dstv = ei + NE;

    k_deg<<<(NE + 255) / 256, 256, 0, stream>>>(dstv, deg);
    k_scanA<<<NBLK, 256, 0, stream>>>(deg, bsum);
    k_scanB<<<1, 128, 0, stream>>>(bsum, boff);
    k_scanC<<<NBLK, 256, 0, stream>>>(deg, boff, rowptr, dinv);
    k_csr<<<(NE + 255) / 256, 256, 0, stream>>>(srcv, dstv, rowptr, csr_src);
    k_gemm1<<<((NN + 63) / 64) * 2, 256, 0, stream>>>(x, W1, h);
    k_agg<<<NN / 4, 256, 0, stream>>>(h, csr_src, rowptr, deg, dinv, b1, batch, pooled);
    k_gemm2<<<NG / 4, 256, 0, stream>>>((const float*)pooled, W2, b2, out);
}

// Round 4
// 199.085 us; speedup vs baseline: 7.6320x; 1.2547x over previous
//
#include <hip/hip_runtime.h>

#define NN 50000
#define NE 800000
#define NG 256
#define NB 256      // buckets
#define BW 196      // nodes per bucket: ceil(NN/NB)
#define EPB 3125    // edges per block in hist/bin passes: NE/256
#define PAD 16      // ints: pad hot atomics to one 64B line each
#define CAP 4608    // max edges per bucket we stage (mean 3125, 26 sigma headroom)

static __device__ __forceinline__ unsigned short f2b(float f) {
    unsigned int u = __float_as_uint(f);
    return (unsigned short)((u + 0x7FFFu + ((u >> 16) & 1u)) >> 16);
}
static __device__ __forceinline__ float blo(unsigned int v) {
    return __uint_as_float((v & 0xFFFFu) << 16);
}
static __device__ __forceinline__ float bhi(unsigned int v) {
    return __uint_as_float(v & 0xFFFF0000u);
}

// 1) global bucket histogram (bucket = dst/BW), padded bins
__global__ __launch_bounds__(256) void k_hist(const int* __restrict__ dst,
                                              int* __restrict__ ghist) {
    __shared__ int lh[NB];
    int t = threadIdx.x;
    lh[t] = 0;
    __syncthreads();
    int e0 = blockIdx.x * EPB;
    for (int i = e0 + t; i < e0 + EPB; i += 256)
        atomicAdd(&lh[(unsigned)dst[i] / BW], 1);
    __syncthreads();
    if (lh[t]) atomicAdd(&ghist[t * PAD], lh[t]);
}

// 2) scan buckets -> bbase[257] and padded cursors
__global__ __launch_bounds__(256) void k_bscan(const int* __restrict__ ghist,
                                               int* __restrict__ bbase,
                                               int* __restrict__ bcur) {
    __shared__ int ps[NB];
    int t = threadIdx.x;
    int v = ghist[t * PAD];
    ps[t] = v;
    __syncthreads();
    for (int o = 1; o < NB; o <<= 1) {
        int u = (t >= o) ? ps[t - o] : 0;
        __syncthreads();
        ps[t] += u;
        __syncthreads();
    }
    int ex = ps[t] - v;
    bbase[t] = ex;
    bcur[t * PAD] = ex;
    if (t == NB - 1) bbase[NB] = NE;
}

// 3) bin edges: packed (src,dst) into bucket-contiguous ebuf
__global__ __launch_bounds__(256) void k_bin(const int* __restrict__ src,
                                             const int* __restrict__ dst,
                                             int* __restrict__ bcur,
                                             int2* __restrict__ ebuf) {
    __shared__ int lh[NB], gb[NB], lc[NB];
    int t = threadIdx.x;
    lh[t] = 0; lc[t] = 0;
    __syncthreads();
    int e0 = blockIdx.x * EPB;
    for (int i = e0 + t; i < e0 + EPB; i += 256)
        atomicAdd(&lh[(unsigned)dst[i] / BW], 1);
    __syncthreads();
    if (lh[t]) gb[t] = atomicAdd(&bcur[t * PAD], lh[t]);
    __syncthreads();
    for (int i = e0 + t; i < e0 + EPB; i += 256) {
        int d = dst[i];
        int b = (unsigned)d / BW;
        int r = atomicAdd(&lc[b], 1);
        ebuf[gb[b] + r] = make_int2(src[i], d);
    }
}

// 4) per-bucket local counting sort -> csr_src (coalesced), rowptr/deg/dinv fused
__global__ __launch_bounds__(256) void k_sort(const int2* __restrict__ ebuf,
                                              const int* __restrict__ bbase,
                                              int* __restrict__ csr_src,
                                              int* __restrict__ rowptr,
                                              int* __restrict__ deg,
                                              float* __restrict__ dinv) {
    __shared__ int hist[NB], off[NB], cur[NB];
    __shared__ int stage[CAP];
    const int t = threadIdx.x;
    const int b = blockIdx.x;
    const int beg = bbase[b];
    const int cnt = bbase[b + 1] - beg;
    const int nbase = b * BW;
    hist[t] = 0; cur[t] = 0;
    __syncthreads();
    for (int i = t; i < cnt; i += 256)
        atomicAdd(&hist[ebuf[beg + i].y - nbase], 1);
    __syncthreads();
    int v = hist[t];
    off[t] = v;
    __syncthreads();
    for (int o = 1; o < NB; o <<= 1) {
        int u = (t >= o) ? off[t - o] : 0;
        __syncthreads();
        off[t] += u;
        __syncthreads();
    }
    int ex = off[t] - v;                 // exclusive prefix
    int gn = nbase + t;
    if (t < BW && gn < NN) {
        rowptr[gn] = beg + ex;
        deg[gn] = v;
        dinv[gn] = rsqrtf((float)(v + 1));
    }
    __syncthreads();
    off[t] = ex;
    __syncthreads();
    for (int i = t; i < cnt; i += 256) {
        int2 e = ebuf[beg + i];
        int l = e.y - nbase;
        int r = atomicAdd(&cur[l], 1);
        stage[off[l] + r] = e.x;
    }
    __syncthreads();
    for (int i = t; i < cnt; i += 256)
        csr_src[beg + i] = stage[i];
}

// 5) h(bf16) = x @ W1 (fp32 accumulate), 64x64 tile, 4x4 outer product
__global__ __launch_bounds__(256) void k_gemm1(const float* __restrict__ x,
                                               const float* __restrict__ W,
                                               unsigned short* __restrict__ h) {
    __shared__ float As[64][64];   // [kk][row]
    __shared__ float Ws[64][64];   // [kk][col]
    const int tid = threadIdx.x;
    const int mt = blockIdx.x >> 1;
    const int c0 = (blockIdx.x & 1) * 64;
    const int r0 = mt * 64;
    const int ty = tid >> 4, tx = tid & 15;
    float acc[4][4];
#pragma unroll
    for (int i = 0; i < 4; ++i)
#pragma unroll
        for (int j = 0; j < 4; ++j) acc[i][j] = 0.f;

    for (int kc = 0; kc < 128; kc += 64) {
        {
            int row = tid & 63;
            int gr = r0 + row;
#pragma unroll
            for (int p = 0; p < 4; ++p) {
                int kk = p * 16 + (tid >> 6) * 4;
                float4 v = make_float4(0.f, 0.f, 0.f, 0.f);
                if (gr < NN) v = *(const float4*)(x + (size_t)gr * 128 + kc + kk);
                As[kk + 0][row] = v.x;
                As[kk + 1][row] = v.y;
                As[kk + 2][row] = v.z;
                As[kk + 3][row] = v.w;
            }
        }
        {
            int c4 = (tid & 15) * 4;
#pragma unroll
            for (int p = 0; p < 4; ++p) {
                int kk = p * 16 + (tid >> 4);
                float4 v = *(const float4*)(W + (size_t)(kc + kk) * 128 + c0 + c4);
                *(float4*)&Ws[kk][c4] = v;
            }
        }
        __syncthreads();
#pragma unroll 4
        for (int kk = 0; kk < 64; ++kk) {
            float4 a4 = *(const float4*)&As[kk][ty * 4];
            float4 b4 = *(const float4*)&Ws[kk][tx * 4];
            float a[4] = {a4.x, a4.y, a4.z, a4.w};
            float bb[4] = {b4.x, b4.y, b4.z, b4.w};
#pragma unroll
            for (int i = 0; i < 4; ++i)
#pragma unroll
                for (int j = 0; j < 4; ++j) acc[i][j] += a[i] * bb[j];
        }
        __syncthreads();
    }
#pragma unroll
    for (int i = 0; i < 4; ++i) {
        int gr = r0 + ty * 4 + i;
        if (gr < NN) {
            ushort4 o;
            o.x = f2b(acc[i][0]);
            o.y = f2b(acc[i][1]);
            o.z = f2b(acc[i][2]);
            o.w = f2b(acc[i][3]);
            *(ushort4*)(h + (size_t)gr * 128 + c0 + tx * 4) = o;
        }
    }
}

// 6) aggregation (bf16 gather) + self-loop + bias + relu + fused max-pool
__global__ __launch_bounds__(256) void k_agg(const unsigned short* __restrict__ h,
                                             const int* __restrict__ csr_src,
                                             const int* __restrict__ rowptr,
                                             const int* __restrict__ deg,
                                             const float* __restrict__ dinv,
                                             const float* __restrict__ b1,
                                             const int* __restrict__ batch,
                                             int* __restrict__ pooled) {
    const int tid = threadIdx.x;
    const int w = tid >> 6, lane = tid & 63;
    const int n = blockIdx.x * 4 + w;        // NN = 12500*4
    __shared__ float vals[4][128];
    __shared__ int bts[4];
    const float dd = dinv[n];
    const int beg = rowptr[n];
    const int end = beg + deg[n];
    const int c = lane * 2;
    float ax = 0.f, ay = 0.f;
#pragma unroll 4
    for (int i = beg; i < end; ++i) {
        int s = csr_src[i];
        float nr = dinv[s] * dd;
        unsigned int v = *(const unsigned int*)(h + (size_t)s * 128 + c);
        ax += blo(v) * nr;
        ay += bhi(v) * nr;
    }
    unsigned int v = *(const unsigned int*)(h + (size_t)n * 128 + c);
    float sl = dd * dd;
    ax = fmaxf(ax + blo(v) * sl + b1[c], 0.f);
    ay = fmaxf(ay + bhi(v) * sl + b1[c + 1], 0.f);
    vals[w][c] = ax;
    vals[w][c + 1] = ay;
    if (lane == 0) bts[w] = batch[n];
    __syncthreads();
    if (tid < 128) {
        float m = vals[0][tid];
        int cur = bts[0];
#pragma unroll
        for (int ww = 1; ww < 4; ++ww) {
            if (bts[ww] != cur) {
                atomicMax(&pooled[cur * 128 + tid], __float_as_int(m));
                cur = bts[ww];
                m = vals[ww][tid];
            } else {
                m = fmaxf(m, vals[ww][tid]);
            }
        }
        atomicMax(&pooled[cur * 128 + tid], __float_as_int(m));
    }
}

// 7) out = relu(pooled @ W2 + b2)
__global__ __launch_bounds__(256) void k_gemm2(const float* __restrict__ pooled,
                                               const float* __restrict__ W2,
                                               const float* __restrict__ b2,
                                               float* __restrict__ out) {
    const int tid = threadIdx.x;
    const int row = blockIdx.x * 4 + (tid >> 6);
    const int col = tid & 63;
    const float* p = pooled + row * 128;
    float acc = b2[col];
    for (int k = 0; k < 128; ++k) acc += p[k] * W2[k * 64 + col];
    out[row * 64 + col] = fmaxf(acc, 0.f);
}

extern "C" void kernel_launch(void* const* d_in, const int* in_sizes, int n_in,
                              void* d_out, int out_size, void* d_ws, size_t ws_size,
                              hipStream_t stream) {
    const float* x     = (const float*)d_in[0];
    const int*   ei    = (const int*)d_in[1];   // [2, NE]: src row then dst row
    const int*   batch = (const int*)d_in[2];
    const float* W1    = (const float*)d_in[3];
    const float* b1    = (const float*)d_in[4];
    const float* W2    = (const float*)d_in[5];
    const float* b2    = (const float*)d_in[6];
    float* out = (float*)d_out;

    // ws layout (int units):
    // [zeroed: pooled NG*128 | ghist NB*PAD] bbase NB+1 (+1 pad) | bcur NB*PAD |
    // rowptr NN | deg NN | dinv NN | csr_src NE | ebuf NE int2 | h NN*128 bf16
    int*   pooled  = (int*)d_ws;
    int*   ghist   = pooled + (size_t)NG * 128;
    int*   bbase   = ghist + NB * PAD;
    int*   bcur    = bbase + NB + 2;
    int*   rowptr  = bcur + NB * PAD;
    int*   deg     = rowptr + NN;
    float* dinv    = (float*)(deg + NN);
    int*   csr_src = (int*)(dinv + NN);
    int2*  ebuf    = (int2*)(csr_src + NE);
    unsigned short* h = (unsigned short*)(ebuf + NE);

    size_t zbytes = ((size_t)NG * 128 + NB * PAD) * 4;
    hipMemsetAsync(d_ws, 0, zbytes, stream);

    const int* srcv = ei;
    const int* dstv = ei + NE;

    k_hist<<<256, 256, 0, stream>>>(dstv, ghist);
    k_bscan<<<1, 256, 0, stream>>>(ghist, bbase, bcur);
    k_bin<<<256, 256, 0, stream>>>(srcv, dstv, bcur, ebuf);
    k_sort<<<NB, 256, 0, stream>>>(ebuf, bbase, csr_src, rowptr, deg, dinv);
    k_gemm1<<<((NN + 63) / 64) * 2, 256, 0, stream>>>(x, W1, h);
    k_agg<<<NN / 4, 256, 0, stream>>>(h, csr_src, rowptr, deg, dinv, b1, batch, pooled);
    k_gemm2<<<NG / 4, 256, 0, stream>>>((const float*)pooled, W2, b2, out);
}

// Round 7
// 185.794 us; speedup vs baseline: 8.1780x; 1.0715x over previous
//
#include <hip/hip_runtime.h>

#define NN 50000
#define NE 800000
#define NG 256
#define NB 256      // buckets
#define BW 196      // nodes per bucket
#define EPB 3125    // edges per block in hist/bin passes
#define PAD 16      // ints: pad hot atomics to one 64B line
#define CAP 4608    // max edges per bucket (mean 3125, ~26 sigma headroom)
#define WT_STRIDE 136  // LDS W-tile row stride in bf16 (272B, 16B-aligned)

typedef __attribute__((ext_vector_type(8))) short bf16x8;
typedef __attribute__((ext_vector_type(4))) float f32x4;

static __device__ __forceinline__ unsigned short f2b(float f) {
    unsigned int u = __float_as_uint(f);
    return (unsigned short)((u + 0x7FFFu + ((u >> 16) & 1u)) >> 16);
}
static __device__ __forceinline__ float blo(unsigned int v) {
    return __uint_as_float((v & 0xFFFFu) << 16);
}
static __device__ __forceinline__ float bhi(unsigned int v) {
    return __uint_as_float(v & 0xFFFF0000u);
}

// 1) global bucket histogram (bucket = dst/BW)
__global__ __launch_bounds__(256) void k_hist(const int* __restrict__ dst,
                                              int* __restrict__ ghist) {
    __shared__ int lh[NB];
    int t = threadIdx.x;
    lh[t] = 0;
    __syncthreads();
    int e0 = blockIdx.x * EPB;
    for (int i = e0 + t; i < e0 + EPB; i += 256)
        atomicAdd(&lh[(unsigned)dst[i] / BW], 1);
    __syncthreads();
    if (lh[t]) atomicAdd(&ghist[t * PAD], lh[t]);
}

// 2) scan buckets -> bbase[257] and padded cursors
__global__ __launch_bounds__(256) void k_bscan(const int* __restrict__ ghist,
                                               int* __restrict__ bbase,
                                               int* __restrict__ bcur) {
    __shared__ int ps[NB];
    int t = threadIdx.x;
    int v = ghist[t * PAD];
    ps[t] = v;
    __syncthreads();
    for (int o = 1; o < NB; o <<= 1) {
        int u = (t >= o) ? ps[t - o] : 0;
        __syncthreads();
        ps[t] += u;
        __syncthreads();
    }
    int ex = ps[t] - v;
    bbase[t] = ex;
    bcur[t * PAD] = ex;
    if (t == NB - 1) bbase[NB] = NE;
}

// 3) bin edges: packed (local_dst<<17 | src) into bucket-contiguous ebuf
__global__ __launch_bounds__(256) void k_bin(const int* __restrict__ src,
                                             const int* __restrict__ dst,
                                             int* __restrict__ bcur,
                                             unsigned int* __restrict__ ebuf) {
    __shared__ int lh[NB], gb[NB], lc[NB];
    int t = threadIdx.x;
    lh[t] = 0; lc[t] = 0;
    __syncthreads();
    int e0 = blockIdx.x * EPB;
    for (int i = e0 + t; i < e0 + EPB; i += 256)
        atomicAdd(&lh[(unsigned)dst[i] / BW], 1);
    __syncthreads();
    if (lh[t]) gb[t] = atomicAdd(&bcur[t * PAD], lh[t]);
    __syncthreads();
    for (int i = e0 + t; i < e0 + EPB; i += 256) {
        int d = dst[i];
        int b = (unsigned)d / BW;
        int r = atomicAdd(&lc[b], 1);
        ebuf[gb[b] + r] = ((unsigned)(d - b * BW) << 17) | (unsigned)src[i];
    }
}

// 4) per-bucket counting sort -> csr_src (coalesced); rowptr/deg/dinv fused
__global__ __launch_bounds__(256) void k_sort(const unsigned int* __restrict__ ebuf,
                                              const int* __restrict__ bbase,
                                              int* __restrict__ csr_src,
                                              int* __restrict__ rowptr,
                                              int* __restrict__ deg,
                                              float* __restrict__ dinv) {
    __shared__ int hist[NB], off[NB], cur[NB];
    __shared__ int stage[CAP];
    const int t = threadIdx.x;
    const int b = blockIdx.x;
    const int beg = bbase[b];
    const int cnt = bbase[b + 1] - beg;
    const int nbase = b * BW;
    hist[t] = 0; cur[t] = 0;
    __syncthreads();
    for (int i = t; i < cnt; i += 256)
        atomicAdd(&hist[ebuf[beg + i] >> 17], 1);
    __syncthreads();
    int v = hist[t];
    off[t] = v;
    __syncthreads();
    for (int o = 1; o < NB; o <<= 1) {
        int u = (t >= o) ? off[t - o] : 0;
        __syncthreads();
        off[t] += u;
        __syncthreads();
    }
    int ex = off[t] - v;
    int gn = nbase + t;
    if (t < BW && gn < NN) {
        rowptr[gn] = beg + ex;
        deg[gn] = v;
        dinv[gn] = rsqrtf((float)(v + 1));
    }
    __syncthreads();
    off[t] = ex;
    __syncthreads();
    for (int i = t; i < cnt; i += 256) {
        unsigned int p = ebuf[beg + i];
        int l = p >> 17;
        int r = atomicAdd(&cur[l], 1);
        stage[off[l] + r] = (int)(p & 0x1FFFFu);
    }
    __syncthreads();
    for (int i = t; i < cnt; i += 256)
        csr_src[beg + i] = stage[i];
}

// 5) W prep: W1 fp32 [k][n] -> Wt bf16 [n][k]
__global__ __launch_bounds__(256) void k_wprep(const float* __restrict__ W,
                                               unsigned short* __restrict__ Wt) {
    int t = threadIdx.x;
    int n = t >> 1, kh = (t & 1) * 64;
    for (int k = kh; k < kh + 64; ++k)
        Wt[n * 128 + k] = f2b(W[k * 128 + n]);
}

// 6) h'(bf16) = dinv * (x @ W1), MFMA 16x16x32 bf16.
//    Block 256 thr = 4 waves; wave = 32 rows x 128 cols.
__global__ __launch_bounds__(256) void k_gemm1(const float* __restrict__ x,
                                               const unsigned short* __restrict__ Wt,
                                               const float* __restrict__ dinv,
                                               unsigned short* __restrict__ h) {
    __shared__ unsigned short Ws[128 * WT_STRIDE];
    const int tid = threadIdx.x;
    {   // stage Wt -> LDS: each thread copies its 64-ushort half-row (8x uint4)
        int n = tid >> 1, kh = (tid & 1) * 64;
        const uint4* s = (const uint4*)(Wt + n * 128 + kh);
        uint4* d = (uint4*)(Ws + n * WT_STRIDE + kh);
#pragma unroll
        for (int p = 0; p < 8; ++p) d[p] = s[p];
    }
    __syncthreads();
    const int w = tid >> 6, lane = tid & 63;
    const int q = lane >> 4, lid = lane & 15;
    const int m0 = blockIdx.x * 128 + w * 32;
    f32x4 acc[2][8];
#pragma unroll
    for (int rt = 0; rt < 2; ++rt)
#pragma unroll
        for (int jt = 0; jt < 8; ++jt) acc[rt][jt] = (f32x4){0.f, 0.f, 0.f, 0.f};

#pragma unroll
    for (int kt = 0; kt < 4; ++kt) {
        bf16x8 a[2];
#pragma unroll
        for (int rt = 0; rt < 2; ++rt) {
            int m = m0 + rt * 16 + lid;
            int k0 = kt * 32 + q * 8;
            float4 p0 = make_float4(0.f, 0.f, 0.f, 0.f), p1 = p0;
            if (m < NN) {
                p0 = *(const float4*)(x + (size_t)m * 128 + k0);
                p1 = *(const float4*)(x + (size_t)m * 128 + k0 + 4);
            }
            a[rt][0] = (short)f2b(p0.x); a[rt][1] = (short)f2b(p0.y);
            a[rt][2] = (short)f2b(p0.z); a[rt][3] = (short)f2b(p0.w);
            a[rt][4] = (short)f2b(p1.x); a[rt][5] = (short)f2b(p1.y);
            a[rt][6] = (short)f2b(p1.z); a[rt][7] = (short)f2b(p1.w);
        }
#pragma unroll
        for (int jt = 0; jt < 8; ++jt) {
            bf16x8 b = *(const bf16x8*)(Ws + (jt * 16 + lid) * WT_STRIDE + kt * 32 + q * 8);
            acc[0][jt] = __builtin_amdgcn_mfma_f32_16x16x32_bf16(a[0], b, acc[0][jt], 0, 0, 0);
            acc[1][jt] = __builtin_amdgcn_mfma_f32_16x16x32_bf16(a[1], b, acc[1][jt], 0, 0, 0);
        }
    }
    // epilogue: C/D layout col=lane&15, row=q*4+reg; scale by dinv, store bf16
#pragma unroll
    for (int rt = 0; rt < 2; ++rt)
#pragma unroll
        for (int reg = 0; reg < 4; ++reg) {
            int gr = m0 + rt * 16 + q * 4 + reg;
            if (gr < NN) {
                float di = dinv[gr];
#pragma unroll
                for (int jt = 0; jt < 8; ++jt)
                    h[(size_t)gr * 128 + jt * 16 + lid] = f2b(acc[rt][jt][reg] * di);
            }
        }
}

// 7) aggregation: agg = dd*(sum_s h'[s] + h'[n]) + b1, relu, fused max-pool.
//    (h' already carries one dinv factor: edge term dinv_s*dd*h_s = dd*h'_s,
//     self-loop dd^2*h_n = dd*h'_n  -- R6 bug was an extra *dd here.)
//    Half-wave per edge (2 edges in flight), lane owns 4 channels (uint2).
__global__ __launch_bounds__(256) void k_agg(const unsigned short* __restrict__ h,
                                             const int* __restrict__ csr_src,
                                             const int* __restrict__ rowptr,
                                             const int* __restrict__ deg,
                                             const float* __restrict__ dinv,
                                             const float* __restrict__ b1,
                                             const int* __restrict__ batch,
                                             int* __restrict__ pooled) {
    const int tid = threadIdx.x;
    const int w = tid >> 6, lane = tid & 63;
    const int half = lane >> 5, sl = lane & 31;
    const int n = blockIdx.x * 4 + w;        // NN = 12500*4
    __shared__ float vals[4][128];
    __shared__ int bts[4];
    const float dd = dinv[n];
    const int beg = rowptr[n];
    const int e = beg + deg[n];
    const int c = sl * 4;
    float a0 = 0.f, a1 = 0.f, a2 = 0.f, a3 = 0.f;
    int i = beg;
#pragma unroll 2
    for (; i + 2 <= e; i += 2) {
        int s = csr_src[i + half];
        uint2 v = *(const uint2*)(h + (size_t)s * 128 + c);
        a0 += blo(v.x); a1 += bhi(v.x); a2 += blo(v.y); a3 += bhi(v.y);
    }
    if (i < e && half == 0) {
        int s = csr_src[i];
        uint2 v = *(const uint2*)(h + (size_t)s * 128 + c);
        a0 += blo(v.x); a1 += bhi(v.x); a2 += blo(v.y); a3 += bhi(v.y);
    }
    a0 += __shfl_xor(a0, 32); a1 += __shfl_xor(a1, 32);
    a2 += __shfl_xor(a2, 32); a3 += __shfl_xor(a3, 32);
    if (half == 0) {
        uint2 hv = *(const uint2*)(h + (size_t)n * 128 + c);
        float4 bb = *(const float4*)(b1 + c);
        a0 = fmaxf(dd * (a0 + blo(hv.x)) + bb.x, 0.f);
        a1 = fmaxf(dd * (a1 + bhi(hv.x)) + bb.y, 0.f);
        a2 = fmaxf(dd * (a2 + blo(hv.y)) + bb.z, 0.f);
        a3 = fmaxf(dd * (a3 + bhi(hv.y)) + bb.w, 0.f);
        *(float4*)&vals[w][c] = make_float4(a0, a1, a2, a3);
    }
    if (lane == 0) bts[w] = batch[n];
    __syncthreads();
    if (tid < 128) {
        float m = vals[0][tid];
        int cur = bts[0];
#pragma unroll
        for (int ww = 1; ww < 4; ++ww) {
            if (bts[ww] != cur) {
                atomicMax(&pooled[cur * 128 + tid], __float_as_int(m));
                cur = bts[ww];
                m = vals[ww][tid];
            } else {
                m = fmaxf(m, vals[ww][tid]);
            }
        }
        atomicMax(&pooled[cur * 128 + tid], __float_as_int(m));
    }
}

// 8) out = relu(pooled @ W2 + b2)
__global__ __launch_bounds__(256) void k_gemm2(const float* __restrict__ pooled,
                                               const float* __restrict__ W2,
                                               const float* __restrict__ b2,
                                               float* __restrict__ out) {
    const int tid = threadIdx.x;
    const int row = blockIdx.x * 4 + (tid >> 6);
    const int col = tid & 63;
    const float* p = pooled + row * 128;
    float acc = b2[col];
    for (int k = 0; k < 128; ++k) acc += p[k] * W2[k * 64 + col];
    out[row * 64 + col] = fmaxf(acc, 0.f);
}

extern "C" void kernel_launch(void* const* d_in, const int* in_sizes, int n_in,
                              void* d_out, int out_size, void* d_ws, size_t ws_size,
                              hipStream_t stream) {
    const float* x     = (const float*)d_in[0];
    const int*   ei    = (const int*)d_in[1];   // [2, NE]: src row then dst row
    const int*   batch = (const int*)d_in[2];
    const float* W1    = (const float*)d_in[3];
    const float* b1    = (const float*)d_in[4];
    const float* W2    = (const float*)d_in[5];
    const float* b2    = (const float*)d_in[6];
    float* out = (float*)d_out;

    // ws layout (int units):
    // [zeroed: pooled NG*128 | ghist NB*PAD] bbase NB+2 | bcur NB*PAD |
    // rowptr NN | deg NN | dinv NN | csr_src NE | ebuf NE uint |
    // Wt 128*128 bf16 | h NN*128 bf16
    int*   pooled  = (int*)d_ws;
    int*   ghist   = pooled + (size_t)NG * 128;
    int*   bbase   = ghist + NB * PAD;
    int*   bcur    = bbase + NB + 2;
    int*   rowptr  = bcur + NB * PAD;
    int*   deg     = rowptr + NN;
    float* dinv    = (float*)(deg + NN);
    int*   csr_src = (int*)(dinv + NN);
    unsigned int* ebuf = (unsigned int*)(csr_src + NE);
    unsigned short* Wt = (unsigned short*)(ebuf + NE);
    unsigned short* h  = Wt + 128 * 128;

    size_t zbytes = ((size_t)NG * 128 + NB * PAD) * 4;
    hipMemsetAsync(d_ws, 0, zbytes, stream);

    const int* srcv = ei;
    const int* dstv = ei + NE;

    k_hist<<<256, 256, 0, stream>>>(dstv, ghist);
    k_bscan<<<1, 256, 0, stream>>>(ghist, bbase, bcur);
    k_bin<<<256, 256, 0, stream>>>(srcv, dstv, bcur, ebuf);
    k_sort<<<NB, 256, 0, stream>>>(ebuf, bbase, csr_src, rowptr, deg, dinv);
    k_wprep<<<1, 256, 0, stream>>>(W1, Wt);
    k_gemm1<<<(NN + 127) / 128, 256, 0, stream>>>(x, Wt, dinv, h);
    k_agg<<<NN / 4, 256, 0, stream>>>(h, csr_src, rowptr, deg, dinv, b1, batch, pooled);
    k_gemm2<<<NG / 4, 256, 0, stream>>>((const float*)pooled, W2, b2, out);
}

// Round 8
// 169.223 us; speedup vs baseline: 8.9788x; 1.0979x over previous
//
#include <hip/hip_runtime.h>

#define NN 50000
#define NE 800000
#define NG 256
#define NB 256        // buckets
#define BW 196        // nodes per bucket
#define NBIN 800      // k_bin blocks
#define EPB 1000      // edges per bin block: NBIN*EPB == NE exactly
#define PAD 16        // ints: pad hot atomics to one 64B line
#define CAP 4608      // fixed ebuf region per bucket (mean 3125, +26 sigma)
#define WT_STRIDE 136 // LDS W-tile row stride in bf16

typedef __attribute__((ext_vector_type(8))) short bf16x8;
typedef __attribute__((ext_vector_type(4))) float f32x4;

static __device__ __forceinline__ unsigned short f2b(float f) {
    unsigned int u = __float_as_uint(f);
    return (unsigned short)((u + 0x7FFFu + ((u >> 16) & 1u)) >> 16);
}
static __device__ __forceinline__ float blo(unsigned int v) {
    return __uint_as_float((v & 0xFFFFu) << 16);
}
static __device__ __forceinline__ float bhi(unsigned int v) {
    return __uint_as_float(v & 0xFFFF0000u);
}

// 1) W prep: W1 fp32 [k][n] -> Wt bf16 [n][k]; 64 blocks, coalesced reads
__global__ __launch_bounds__(256) void k_wprep(const float* __restrict__ W,
                                               unsigned short* __restrict__ Wt) {
    int g = blockIdx.x * 256 + threadIdx.x;   // 0..16383
    int k = g >> 7, n = g & 127;
    Wt[n * 128 + k] = f2b(W[g]);
}

// 2) bin edges into fixed per-bucket regions of ebuf (no pre-scan needed).
//    Per-block LDS hist -> one reservation atomic per (block,bucket) -> scatter.
__global__ __launch_bounds__(256) void k_bin(const int* __restrict__ src,
                                             const int* __restrict__ dst,
                                             int* __restrict__ bcur,
                                             unsigned int* __restrict__ ebuf) {
    __shared__ int lh[NB], gb[NB], lc[NB];
    int t = threadIdx.x;
    lh[t] = 0; lc[t] = 0;
    __syncthreads();
    int e0 = blockIdx.x * EPB;
    for (int i = e0 + t; i < e0 + EPB; i += 256)
        atomicAdd(&lh[(unsigned)dst[i] / BW], 1);
    __syncthreads();
    if (lh[t]) gb[t] = t * CAP + atomicAdd(&bcur[t * PAD], lh[t]);
    __syncthreads();
    for (int i = e0 + t; i < e0 + EPB; i += 256) {   // dst re-read is L1-hot (4KB)
        int d = dst[i];
        int b = (unsigned)d / BW;
        int r = atomicAdd(&lc[b], 1);
        ebuf[gb[b] + r] = ((unsigned)(d - b * BW) << 17) | (unsigned)src[i];
    }
}

// 3) per-bucket counting sort. Global base = local 256-scan of final counts
//    (redundant per block, ~free). Outputs csr_src coalesced + rowptr/deg/dinv.
__global__ __launch_bounds__(256) void k_sort(const unsigned int* __restrict__ ebuf,
                                              const int* __restrict__ bcur,
                                              int* __restrict__ csr_src,
                                              int* __restrict__ rowptr,
                                              int* __restrict__ deg,
                                              float* __restrict__ dinv) {
    __shared__ int hist[NB], off[NB], cur[NB], ps[NB];
    __shared__ int stage[CAP];
    const int t = threadIdx.x;
    const int b = blockIdx.x;
    // global exclusive base for this bucket
    int cv = bcur[t * PAD];
    ps[t] = cv;
    __syncthreads();
    for (int o = 1; o < NB; o <<= 1) {
        int u = (t >= o) ? ps[t - o] : 0;
        __syncthreads();
        ps[t] += u;
        __syncthreads();
    }
    const int cnt = bcur[b * PAD];
    const int base = ps[b] - cnt;     // exclusive prefix
    const int ebeg = b * CAP;
    const int nbase = b * BW;
    hist[t] = 0; cur[t] = 0;
    __syncthreads();
    for (int i = t; i < cnt; i += 256)
        atomicAdd(&hist[ebuf[ebeg + i] >> 17], 1);
    __syncthreads();
    int v = hist[t];
    off[t] = v;
    __syncthreads();
    for (int o = 1; o < NB; o <<= 1) {
        int u = (t >= o) ? off[t - o] : 0;
        __syncthreads();
        off[t] += u;
        __syncthreads();
    }
    int ex = off[t] - v;
    int gn = nbase + t;
    if (t < BW && gn < NN) {
        rowptr[gn] = base + ex;
        deg[gn] = v;
        dinv[gn] = rsqrtf((float)(v + 1));
    }
    __syncthreads();
    off[t] = ex;
    __syncthreads();
    for (int i = t; i < cnt; i += 256) {
        unsigned int p = ebuf[ebeg + i];
        int l = p >> 17;
        int r = atomicAdd(&cur[l], 1);
        stage[off[l] + r] = (int)(p & 0x1FFFFu);
    }
    __syncthreads();
    for (int i = t; i < cnt; i += 256)
        csr_src[base + i] = stage[i];
}

// 4) h'(bf16) = dinv * (x @ W1), MFMA 16x16x32 bf16.
__global__ __launch_bounds__(256) void k_gemm1(const float* __restrict__ x,
                                               const unsigned short* __restrict__ Wt,
                                               const float* __restrict__ dinv,
                                               unsigned short* __restrict__ h) {
    __shared__ unsigned short Ws[128 * WT_STRIDE];
    const int tid = threadIdx.x;
    {   // stage Wt -> LDS: each thread copies its 64-ushort half-row (8x uint4)
        int n = tid >> 1, kh = (tid & 1) * 64;
        const uint4* s = (const uint4*)(Wt + n * 128 + kh);
        uint4* d = (uint4*)(Ws + n * WT_STRIDE + kh);
#pragma unroll
        for (int p = 0; p < 8; ++p) d[p] = s[p];
    }
    __syncthreads();
    const int w = tid >> 6, lane = tid & 63;
    const int q = lane >> 4, lid = lane & 15;
    const int m0 = blockIdx.x * 128 + w * 32;
    f32x4 acc[2][8];
#pragma unroll
    for (int rt = 0; rt < 2; ++rt)
#pragma unroll
        for (int jt = 0; jt < 8; ++jt) acc[rt][jt] = (f32x4){0.f, 0.f, 0.f, 0.f};

#pragma unroll
    for (int kt = 0; kt < 4; ++kt) {
        bf16x8 a[2];
#pragma unroll
        for (int rt = 0; rt < 2; ++rt) {
            int m = m0 + rt * 16 + lid;
            int k0 = kt * 32 + q * 8;
            float4 p0 = make_float4(0.f, 0.f, 0.f, 0.f), p1 = p0;
            if (m < NN) {
                p0 = *(const float4*)(x + (size_t)m * 128 + k0);
                p1 = *(const float4*)(x + (size_t)m * 128 + k0 + 4);
            }
            a[rt][0] = (short)f2b(p0.x); a[rt][1] = (short)f2b(p0.y);
            a[rt][2] = (short)f2b(p0.z); a[rt][3] = (short)f2b(p0.w);
            a[rt][4] = (short)f2b(p1.x); a[rt][5] = (short)f2b(p1.y);
            a[rt][6] = (short)f2b(p1.z); a[rt][7] = (short)f2b(p1.w);
        }
#pragma unroll
        for (int jt = 0; jt < 8; ++jt) {
            bf16x8 b = *(const bf16x8*)(Ws + (jt * 16 + lid) * WT_STRIDE + kt * 32 + q * 8);
            acc[0][jt] = __builtin_amdgcn_mfma_f32_16x16x32_bf16(a[0], b, acc[0][jt], 0, 0, 0);
            acc[1][jt] = __builtin_amdgcn_mfma_f32_16x16x32_bf16(a[1], b, acc[1][jt], 0, 0, 0);
        }
    }
#pragma unroll
    for (int rt = 0; rt < 2; ++rt)
#pragma unroll
        for (int reg = 0; reg < 4; ++reg) {
            int gr = m0 + rt * 16 + q * 4 + reg;
            if (gr < NN) {
                float di = dinv[gr];
#pragma unroll
                for (int jt = 0; jt < 8; ++jt)
                    h[(size_t)gr * 128 + jt * 16 + lid] = f2b(acc[rt][jt][reg] * di);
            }
        }
}

// 5) aggregation: agg = dd*(sum_s h'[s] + h'[n]) + b1, relu, fused max-pool.
//    Quarter-wave per edge: 16 lanes x uint4 (8 ch), 4 edges in flight/wave.
__global__ __launch_bounds__(256) void k_agg(const unsigned short* __restrict__ h,
                                             const int* __restrict__ csr_src,
                                             const int* __restrict__ rowptr,
                                             const int* __restrict__ deg,
                                             const float* __restrict__ dinv,
                                             const float* __restrict__ b1,
                                             const int* __restrict__ batch,
                                             int* __restrict__ pooled) {
    const int tid = threadIdx.x;
    const int w = tid >> 6, lane = tid & 63;
    const int q = lane >> 4, ql = lane & 15;
    const int n = blockIdx.x * 4 + w;        // NN = 12500*4
    __shared__ float vals[4][128];
    __shared__ int bts[4];
    const float dd = dinv[n];
    const int beg = rowptr[n];
    const int end = beg + deg[n];
    const int c = ql * 8;
    float a[8];
#pragma unroll
    for (int j = 0; j < 8; ++j) a[j] = 0.f;
#pragma unroll 2
    for (int i = beg + q; i < end; i += 4) {
        int s = csr_src[i];
        uint4 v = *(const uint4*)(h + (size_t)s * 128 + c);
        a[0] += blo(v.x); a[1] += bhi(v.x);
        a[2] += blo(v.y); a[3] += bhi(v.y);
        a[4] += blo(v.z); a[5] += bhi(v.z);
        a[6] += blo(v.w); a[7] += bhi(v.w);
    }
#pragma unroll
    for (int j = 0; j < 8; ++j) {
        a[j] += __shfl_xor(a[j], 16);
        a[j] += __shfl_xor(a[j], 32);
    }
    if (q == 0) {
        uint4 hv = *(const uint4*)(h + (size_t)n * 128 + c);
        float4 b0 = *(const float4*)(b1 + c);
        float4 b4 = *(const float4*)(b1 + c + 4);
        float r0 = fmaxf(dd * (a[0] + blo(hv.x)) + b0.x, 0.f);
        float r1 = fmaxf(dd * (a[1] + bhi(hv.x)) + b0.y, 0.f);
        float r2 = fmaxf(dd * (a[2] + blo(hv.y)) + b0.z, 0.f);
        float r3 = fmaxf(dd * (a[3] + bhi(hv.y)) + b0.w, 0.f);
        float r4 = fmaxf(dd * (a[4] + blo(hv.z)) + b4.x, 0.f);
        float r5 = fmaxf(dd * (a[5] + bhi(hv.z)) + b4.y, 0.f);
        float r6 = fmaxf(dd * (a[6] + blo(hv.w)) + b4.z, 0.f);
        float r7 = fmaxf(dd * (a[7] + bhi(hv.w)) + b4.w, 0.f);
        *(float4*)&vals[w][c] = make_float4(r0, r1, r2, r3);
        *(float4*)&vals[w][c + 4] = make_float4(r4, r5, r6, r7);
    }
    if (lane == 0) bts[w] = batch[n];
    __syncthreads();
    if (tid < 128) {
        float m = vals[0][tid];
        int cur = bts[0];
#pragma unroll
        for (int ww = 1; ww < 4; ++ww) {
            if (bts[ww] != cur) {
                atomicMax(&pooled[cur * 128 + tid], __float_as_int(m));
                cur = bts[ww];
                m = vals[ww][tid];
            } else {
                m = fmaxf(m, vals[ww][tid]);
            }
        }
        atomicMax(&pooled[cur * 128 + tid], __float_as_int(m));
    }
}

// 6) out = relu(pooled @ W2 + b2)
__global__ __launch_bounds__(256) void k_gemm2(const float* __restrict__ pooled,
                                               const float* __restrict__ W2,
                                               const float* __restrict__ b2,
                                               float* __restrict__ out) {
    const int tid = threadIdx.x;
    const int row = blockIdx.x * 4 + (tid >> 6);
    const int col = tid & 63;
    const float* p = pooled + row * 128;
    float acc = b2[col];
    for (int k = 0; k < 128; ++k) acc += p[k] * W2[k * 64 + col];
    out[row * 64 + col] = fmaxf(acc, 0.f);
}

extern "C" void kernel_launch(void* const* d_in, const int* in_sizes, int n_in,
                              void* d_out, int out_size, void* d_ws, size_t ws_size,
                              hipStream_t stream) {
    const float* x     = (const float*)d_in[0];
    const int*   ei    = (const int*)d_in[1];   // [2, NE]: src row then dst row
    const int*   batch = (const int*)d_in[2];
    const float* W1    = (const float*)d_in[3];
    const float* b1    = (const float*)d_in[4];
    const float* W2    = (const float*)d_in[5];
    const float* b2    = (const float*)d_in[6];
    float* out = (float*)d_out;

    // ws layout (int units):
    // [zeroed: pooled NG*128 | bcur NB*PAD] rowptr NN | deg NN | dinv NN |
    // csr_src NE | ebuf NB*CAP | Wt 128*128 bf16 | h NN*128 bf16
    int*   pooled  = (int*)d_ws;
    int*   bcur    = pooled + (size_t)NG * 128;
    int*   rowptr  = bcur + NB * PAD;
    int*   deg     = rowptr + NN;
    float* dinv    = (float*)(deg + NN);
    int*   csr_src = (int*)(dinv + NN);
    unsigned int* ebuf = (unsigned int*)(csr_src + NE);
    unsigned short* Wt = (unsigned short*)(ebuf + (size_t)NB * CAP);
    unsigned short* h  = Wt + 128 * 128;

    size_t zbytes = ((size_t)NG * 128 + NB * PAD) * 4;
    hipMemsetAsync(d_ws, 0, zbytes, stream);

    const int* srcv = ei;
    const int* dstv = ei + NE;

    k_wprep<<<64, 256, 0, stream>>>(W1, Wt);
    k_bin<<<NBIN, 256, 0, stream>>>(srcv, dstv, bcur, ebuf);
    k_sort<<<NB, 256, 0, stream>>>(ebuf, bcur, csr_src, rowptr, deg, dinv);
    k_gemm1<<<(NN + 127) / 128, 256, 0, stream>>>(x, Wt, dinv, h);
    k_agg<<<NN / 4, 256, 0, stream>>>(h, csr_src, rowptr, deg, dinv, b1, batch, pooled);
    k_gemm2<<<NG / 4, 256, 0, stream>>>((const float*)pooled, W2, b2, out);
}

// Round 9
// 164.599 us; speedup vs baseline: 9.2310x; 1.0281x over previous
//
#include <hip/hip_runtime.h>

#define NN 50000
#define NE 800000
#define NG 256
#define NB 256        // buckets
#define BW 196        // nodes per bucket
#define NBIN 800      // k_bin blocks
#define EPB 1000      // edges per bin block: NBIN*EPB == NE
#define PAD 16        // ints: pad hot atomics to one 64B line
#define CAP 4608      // fixed region per bucket (mean 3125, +26 sigma)
#define WT_STRIDE 136 // LDS W-tile row stride in bf16

typedef __attribute__((ext_vector_type(8))) short bf16x8;
typedef __attribute__((ext_vector_type(4))) float f32x4;

static __device__ __forceinline__ unsigned short f2b(float f) {
    unsigned int u = __float_as_uint(f);
    return (unsigned short)((u + 0x7FFFu + ((u >> 16) & 1u)) >> 16);
}
static __device__ __forceinline__ float blo(unsigned int v) {
    return __uint_as_float((v & 0xFFFFu) << 16);
}
static __device__ __forceinline__ float bhi(unsigned int v) {
    return __uint_as_float(v & 0xFFFF0000u);
}

// 1) bin edges into fixed per-bucket regions of ebuf.
__global__ __launch_bounds__(256) void k_bin(const int* __restrict__ src,
                                             const int* __restrict__ dst,
                                             int* __restrict__ bcur,
                                             unsigned int* __restrict__ ebuf) {
    __shared__ int lh[NB], gb[NB], lc[NB];
    int t = threadIdx.x;
    lh[t] = 0; lc[t] = 0;
    __syncthreads();
    int e0 = blockIdx.x * EPB;
    for (int i = e0 + t; i < e0 + EPB; i += 256)
        atomicAdd(&lh[(unsigned)dst[i] / BW], 1);
    __syncthreads();
    if (lh[t]) gb[t] = t * CAP + atomicAdd(&bcur[t * PAD], lh[t]);
    __syncthreads();
    for (int i = e0 + t; i < e0 + EPB; i += 256) {   // dst re-read is L1-hot
        int d = dst[i];
        int b = (unsigned)d / BW;
        int r = atomicAdd(&lc[b], 1);
        ebuf[gb[b] + r] = ((unsigned)(d - b * BW) << 17) | (unsigned)src[i];
    }
}

// 2) per-bucket counting sort into bucket-local csr region [b*CAP, b*CAP+cnt).
//    rowptr is a global index into csr_src; no cross-bucket scan needed.
__global__ __launch_bounds__(256) void k_sort(const unsigned int* __restrict__ ebuf,
                                              const int* __restrict__ bcur,
                                              int* __restrict__ csr_src,
                                              int* __restrict__ rowptr,
                                              int* __restrict__ deg,
                                              float* __restrict__ dinv) {
    __shared__ int hist[NB], off[NB], cur[NB];
    __shared__ int stage[CAP];
    const int t = threadIdx.x;
    const int b = blockIdx.x;
    const int cnt = bcur[b * PAD];
    const int ebeg = b * CAP;
    const int nbase = b * BW;
    hist[t] = 0; cur[t] = 0;
    __syncthreads();
    for (int i = t; i < cnt; i += 256)
        atomicAdd(&hist[ebuf[ebeg + i] >> 17], 1);
    __syncthreads();
    int v = hist[t];
    off[t] = v;
    __syncthreads();
    for (int o = 1; o < NB; o <<= 1) {
        int u = (t >= o) ? off[t - o] : 0;
        __syncthreads();
        off[t] += u;
        __syncthreads();
    }
    int ex = off[t] - v;
    int gn = nbase + t;
    if (t < BW && gn < NN) {
        rowptr[gn] = ebeg + ex;
        deg[gn] = v;
        dinv[gn] = rsqrtf((float)(v + 1));
    }
    __syncthreads();
    off[t] = ex;
    __syncthreads();
    for (int i = t; i < cnt; i += 256) {
        unsigned int p = ebuf[ebeg + i];
        int l = p >> 17;
        int r = atomicAdd(&cur[l], 1);
        stage[off[l] + r] = (int)(p & 0x1FFFFu);
    }
    __syncthreads();
    for (int i = t; i < cnt; i += 256)
        csr_src[ebeg + i] = stage[i];
}

// 3) h'(bf16) = dinv * (x @ W1), MFMA 16x16x32 bf16.
//    W1 transposed+bf16-converted straight into LDS per block (64KB, L2-hot).
__global__ __launch_bounds__(256) void k_gemm1(const float* __restrict__ x,
                                               const float* __restrict__ W,
                                               const float* __restrict__ dinv,
                                               unsigned short* __restrict__ h) {
    __shared__ unsigned short Ws[128 * WT_STRIDE];
    const int tid = threadIdx.x;
#pragma unroll
    for (int p = 0; p < 64; ++p) {           // 256 thr x 64 = 16384 = 128x128
        int g = p * 256 + tid;
        int k = g >> 7, n = g & 127;         // coalesced read of W[k][n]
        Ws[n * WT_STRIDE + k] = f2b(W[g]);
    }
    __syncthreads();
    const int w = tid >> 6, lane = tid & 63;
    const int q = lane >> 4, lid = lane & 15;
    const int m0 = blockIdx.x * 128 + w * 32;
    f32x4 acc[2][8];
#pragma unroll
    for (int rt = 0; rt < 2; ++rt)
#pragma unroll
        for (int jt = 0; jt < 8; ++jt) acc[rt][jt] = (f32x4){0.f, 0.f, 0.f, 0.f};

#pragma unroll
    for (int kt = 0; kt < 4; ++kt) {
        bf16x8 a[2];
#pragma unroll
        for (int rt = 0; rt < 2; ++rt) {
            int m = m0 + rt * 16 + lid;
            int k0 = kt * 32 + q * 8;
            float4 p0 = make_float4(0.f, 0.f, 0.f, 0.f), p1 = p0;
            if (m < NN) {
                p0 = *(const float4*)(x + (size_t)m * 128 + k0);
                p1 = *(const float4*)(x + (size_t)m * 128 + k0 + 4);
            }
            a[rt][0] = (short)f2b(p0.x); a[rt][1] = (short)f2b(p0.y);
            a[rt][2] = (short)f2b(p0.z); a[rt][3] = (short)f2b(p0.w);
            a[rt][4] = (short)f2b(p1.x); a[rt][5] = (short)f2b(p1.y);
            a[rt][6] = (short)f2b(p1.z); a[rt][7] = (short)f2b(p1.w);
        }
#pragma unroll
        for (int jt = 0; jt < 8; ++jt) {
            bf16x8 b = *(const bf16x8*)(Ws + (jt * 16 + lid) * WT_STRIDE + kt * 32 + q * 8);
            acc[0][jt] = __builtin_amdgcn_mfma_f32_16x16x32_bf16(a[0], b, acc[0][jt], 0, 0, 0);
            acc[1][jt] = __builtin_amdgcn_mfma_f32_16x16x32_bf16(a[1], b, acc[1][jt], 0, 0, 0);
        }
    }
#pragma unroll
    for (int rt = 0; rt < 2; ++rt)
#pragma unroll
        for (int reg = 0; reg < 4; ++reg) {
            int gr = m0 + rt * 16 + q * 4 + reg;
            if (gr < NN) {
                float di = dinv[gr];
#pragma unroll
                for (int jt = 0; jt < 8; ++jt)
                    h[(size_t)gr * 128 + jt * 16 + lid] = f2b(acc[rt][jt][reg] * di);
            }
        }
}

// 4) aggregation: quarter-wave (16 lanes x 8ch uint4) owns ONE dst node.
//    No cross-lane reduction; per-lane independent gather chains, unroll 4.
//    Block = 16 dsts; fused bias+relu+sorted-batch max-pool.
__global__ __launch_bounds__(256) void k_agg(const unsigned short* __restrict__ h,
                                             const int* __restrict__ csr_src,
                                             const int* __restrict__ rowptr,
                                             const int* __restrict__ deg,
                                             const float* __restrict__ dinv,
                                             const float* __restrict__ b1,
                                             const int* __restrict__ batch,
                                             int* __restrict__ pooled) {
    const int tid = threadIdx.x;
    const int qg = tid >> 4, ql = tid & 15;
    const int n = blockIdx.x * 16 + qg;      // NN = 3125*16, no tail
    __shared__ float vals[16][128];
    __shared__ int bts[16];
    if (ql == 0) bts[qg] = batch[n];
    const float dd = dinv[n];
    const int beg = rowptr[n];
    const int end = beg + deg[n];
    const int c = ql * 8;
    float a[8];
#pragma unroll
    for (int j = 0; j < 8; ++j) a[j] = 0.f;
#pragma unroll 4
    for (int i = beg; i < end; ++i) {
        int s = csr_src[i];
        uint4 v = *(const uint4*)(h + (size_t)s * 128 + c);
        a[0] += blo(v.x); a[1] += bhi(v.x);
        a[2] += blo(v.y); a[3] += bhi(v.y);
        a[4] += blo(v.z); a[5] += bhi(v.z);
        a[6] += blo(v.w); a[7] += bhi(v.w);
    }
    {
        uint4 hv = *(const uint4*)(h + (size_t)n * 128 + c);
        float4 b0 = *(const float4*)(b1 + c);
        float4 b4 = *(const float4*)(b1 + c + 4);
        float r0 = fmaxf(dd * (a[0] + blo(hv.x)) + b0.x, 0.f);
        float r1 = fmaxf(dd * (a[1] + bhi(hv.x)) + b0.y, 0.f);
        float r2 = fmaxf(dd * (a[2] + blo(hv.y)) + b0.z, 0.f);
        float r3 = fmaxf(dd * (a[3] + bhi(hv.y)) + b0.w, 0.f);
        float r4 = fmaxf(dd * (a[4] + blo(hv.z)) + b4.x, 0.f);
        float r5 = fmaxf(dd * (a[5] + bhi(hv.z)) + b4.y, 0.f);
        float r6 = fmaxf(dd * (a[6] + blo(hv.w)) + b4.z, 0.f);
        float r7 = fmaxf(dd * (a[7] + bhi(hv.w)) + b4.w, 0.f);
        *(float4*)&vals[qg][c] = make_float4(r0, r1, r2, r3);
        *(float4*)&vals[qg][c + 4] = make_float4(r4, r5, r6, r7);
    }
    __syncthreads();
    if (tid < 128) {
        float m = vals[0][tid];
        int cur = bts[0];
#pragma unroll
        for (int ww = 1; ww < 16; ++ww) {
            if (bts[ww] != cur) {
                atomicMax(&pooled[cur * 128 + tid], __float_as_int(m));
                cur = bts[ww];
                m = vals[ww][tid];
            } else {
                m = fmaxf(m, vals[ww][tid]);
            }
        }
        atomicMax(&pooled[cur * 128 + tid], __float_as_int(m));
    }
}

// 5) out = relu(pooled @ W2 + b2)
__global__ __launch_bounds__(256) void k_gemm2(const float* __restrict__ pooled,
                                               const float* __restrict__ W2,
                                               const float* __restrict__ b2,
                                               float* __restrict__ out) {
    const int tid = threadIdx.x;
    const int row = blockIdx.x * 4 + (tid >> 6);
    const int col = tid & 63;
    const float* p = pooled + row * 128;
    float acc = b2[col];
    for (int k = 0; k < 128; ++k) acc += p[k] * W2[k * 64 + col];
    out[row * 64 + col] = fmaxf(acc, 0.f);
}

extern "C" void kernel_launch(void* const* d_in, const int* in_sizes, int n_in,
                              void* d_out, int out_size, void* d_ws, size_t ws_size,
                              hipStream_t stream) {
    const float* x     = (const float*)d_in[0];
    const int*   ei    = (const int*)d_in[1];   // [2, NE]: src row then dst row
    const int*   batch = (const int*)d_in[2];
    const float* W1    = (const float*)d_in[3];
    const float* b1    = (const float*)d_in[4];
    const float* W2    = (const float*)d_in[5];
    const float* b2    = (const float*)d_in[6];
    float* out = (float*)d_out;

    // ws layout (int units):
    // [zeroed: pooled NG*128 | bcur NB*PAD] rowptr NN | deg NN | dinv NN |
    // csr_src NB*CAP | ebuf NB*CAP | h NN*128 bf16
    int*   pooled  = (int*)d_ws;
    int*   bcur    = pooled + (size_t)NG * 128;
    int*   rowptr  = bcur + NB * PAD;
    int*   deg     = rowptr + NN;
    float* dinv    = (float*)(deg + NN);
    int*   csr_src = (int*)(dinv + NN);
    unsigned int* ebuf = (unsigned int*)(csr_src + (size_t)NB * CAP);
    unsigned short* h  = (unsigned short*)(ebuf + (size_t)NB * CAP);

    size_t zbytes = ((size_t)NG * 128 + NB * PAD) * 4;
    hipMemsetAsync(d_ws, 0, zbytes, stream);

    const int* srcv = ei;
    const int* dstv = ei + NE;

    k_bin<<<NBIN, 256, 0, stream>>>(srcv, dstv, bcur, ebuf);
    k_sort<<<NB, 256, 0, stream>>>(ebuf, bcur, csr_src, rowptr, deg, dinv);
    k_gemm1<<<(NN + 127) / 128, 256, 0, stream>>>(x, W1, dinv, h);
    k_agg<<<NN / 16, 256, 0, stream>>>(h, csr_src, rowptr, deg, dinv, b1, batch, pooled);
    k_gemm2<<<NG / 4, 256, 0, stream>>>((const float*)pooled, W2, b2, out);
}